// Round 5
// baseline (127.210 us; speedup 1.0000x reference)
//
#include <hip/hip_runtime.h>

// ROI align-style pooling (bilinear), matches reference _pool_one_roi exactly.
// img: (1,128,128,1024) f32, rois: (1,256,4) f32 (x,y,w,h in pixels)
// out: (1,256,7,7,1024) f32
//
// R9b: identical to R9 (Round-4 bench died on container acquire, not kernel).
//   Channel-sliced, phase-sequenced for L2 residency.
//   Diagnosis: R5-R8 all issue ~160MB of post-L1 image reads that miss the
//   per-XCD L2 (working set ~21MB vs 4MB) -> ~140MB served by L3/HBM at
//   ~6-8 TB/s = the invariant ~33us kernel cost. Warm pass (R8) was null ->
//   location (L3 vs HBM) doesn't matter, volume does.
//   Fix: 32 slices x 32 channels (2MB image footprint per slice). All 256
//   blocks (one per ROI) of a slice land on ONE XCD via the b%8 round-robin;
//   4 phases sequence through dispatch order (exactly 2048 blocks resident =
//   one phase). Per-XCD L2 holds one 2MB slice -> cross-ROI re-reads hit L2
//   (34.5 TB/s); post-L2 reads collapse to compulsory 64MB. Floor ~18-20us.

#define IMG_H 128
#define IMG_W 128
#define IMG_C 1024
#define POOLK 7
#define NROIS 256

#define SLICE_C 32                  // 32 ch * 4B = 128 B per pixel-slice
#define NSLICE (IMG_C / SLICE_C)    // 32
#define NXCD 8
#define NPHASE (NSLICE / NXCD)      // 4
#define NBLK (NROIS * NSLICE)       // 8192

typedef float vfloat4 __attribute__((ext_vector_type(4)));

__global__ __launch_bounds__(256, 8) void roi_pool_kernel(
    const float* __restrict__ img,
    const float* __restrict__ rois,
    float* __restrict__ out) {
  // b = ((phase*NROIS) + roi)*8 + x  ->  hw xcd = b%8 = x; slice = phase*8+x.
  const int b = (int)blockIdx.x;
  const int x8 = b & 7;
  const int k = b >> 3;
  const int r = k & (NROIS - 1);
  const int phase = k >> 8;
  const int slice = phase * NXCD + x8;
  const int cbase = slice * SLICE_C;

  // Block-uniform ROI geometry -> SGPRs.
  const vfloat4 roi = *(const vfloat4*)(rois + (size_t)r * 4);
  const int x0 = __builtin_amdgcn_readfirstlane((int)(roi.x * 0.0625f));
  const int y0 = __builtin_amdgcn_readfirstlane((int)(roi.y * 0.0625f));
  const int w  = __builtin_amdgcn_readfirstlane((int)(roi.z * 0.0625f));
  const int h  = __builtin_amdgcn_readfirstlane((int)(roi.w * 0.0625f));

  const float step_y = (float)h * (1.0f / 7.0f);
  const float step_x = (float)w * (1.0f / 7.0f);
  const int ymax = max(h - 1, 0);
  const int xmax = max(w - 1, 0);

  // Thread -> (cell, channel-lane): 8 lanes x float4 = 32 ch; 32 cell-groups.
  const int lane  = (int)threadIdx.x & 7;
  const int cell0 = (int)threadIdx.x >> 3;     // 0..31
  const int coff  = cbase + lane * 4;

#pragma unroll
  for (int half = 0; half < 2; ++half) {
    const int cell = cell0 + half * 32;        // 0..63; 49 active
    if (cell < POOLK * POOLK) {
      const int iy = cell / POOLK;
      const int ix = cell - iy * POOLK;

      // y geometry (per reference)
      const float sy = (float)iy * step_y;
      const float fy = floorf(sy);
      const float ty = sy - fy;
      const int y_lo = (int)fy;
      const int y_hi = min(y_lo + 1, ymax);
      const int gy0 = min(max(y0 + y_lo, 0), IMG_H - 1);
      const int gy1 = min(max(y0 + y_hi, 0), IMG_H - 1);

      // x geometry (per reference)
      const float sx = (float)ix * step_x;
      const float fx = floorf(sx);
      const float tx = sx - fx;
      const int x_lo = (int)fx;
      const int x_hi = min(x_lo + 1, xmax);
      const int gx0 = min(max(x0 + x_lo, 0), IMG_W - 1);
      const int gx1 = min(max(x0 + x_hi, 0), IMG_W - 1);

      const float* r0 = img + (size_t)(gy0 * IMG_W) * IMG_C + coff;
      const float* r1 = img + (size_t)(gy1 * IMG_W) * IMG_C + coff;

      const vfloat4 v00 = *(const vfloat4*)(r0 + (size_t)gx0 * IMG_C);
      const vfloat4 v01 = *(const vfloat4*)(r0 + (size_t)gx1 * IMG_C);
      const vfloat4 v10 = *(const vfloat4*)(r1 + (size_t)gx0 * IMG_C);
      const vfloat4 v11 = *(const vfloat4*)(r1 + (size_t)gx1 * IMG_C);

      const vfloat4 top = v00 + tx * (v01 - v00);
      const vfloat4 bot = v10 + tx * (v11 - v10);
      const vfloat4 o   = top + ty * (bot - top);

      float* op = out + (((size_t)r * POOLK + iy) * POOLK + ix) * IMG_C + coff;
      __builtin_nontemporal_store(o, (vfloat4*)op);
    }
  }
}

extern "C" void kernel_launch(void* const* d_in, const int* in_sizes, int n_in,
                              void* d_out, int out_size, void* d_ws, size_t ws_size,
                              hipStream_t stream) {
  const float* img  = (const float*)d_in[0];   // 1*128*128*1024
  const float* rois = (const float*)d_in[1];   // 1*256*4
  float* out = (float*)d_out;                  // 1*256*7*7*1024

  dim3 grid(NBLK);    // 8192: phase-major -> one 2MB slice per XCD at a time
  dim3 block(256);
  roi_pool_kernel<<<grid, block, 0, stream>>>(img, rois, out);
}

// Round 6
// 118.849 us; speedup vs baseline: 1.0703x; 1.0703x over previous
//
#include <hip/hip_runtime.h>

// ROI align-style pooling (bilinear), matches reference _pool_one_roi exactly.
// img: (1,128,128,1024) f32, rois: (1,256,4) f32 (x,y,w,h in pixels)
// out: (1,256,7,7,1024) f32
//
// R10: R7 strip-per-block structure (4KB-contiguous per-pixel access, the
//   known-good ~34us kernel) + block-UNIFORM load elision:
//   - ix==0 has tx==0 -> v01/v11 never affect the result (top=v00 exactly).
//   - ty==0 (all iy==0 strips) or gy1==gy0 (small/clamped h) -> row1 unused.
//   - tx==0 or gx1==gx0 (small/clamped w) -> column-hi unused.
//   All predicates derive from readfirstlane'd scalars + uniform ix/iy ->
//   s_cbranch, no divergence. Cuts raw post-L1 reads ~20% (186->~148MB).
//   R9 lesson: L2-residency via channel slicing is structurally impossible
//   (needs granule <=340B for 4MB L2 residency, >=1KB for DRAM efficiency);
//   R8 lesson: L3-vs-HBM location is irrelevant. Volume is the last lever.

#define IMG_H 128
#define IMG_W 128
#define IMG_C 1024
#define POOLK 7
#define NROIS 256
#define NBLK (POOLK * NROIS)   // 1792
#define NXCD 8
#define CHUNK (NBLK / NXCD)    // 224  (1792 % 8 == 0 -> bijective swizzle)

typedef float vfloat4 __attribute__((ext_vector_type(4)));

__global__ __launch_bounds__(256, 8) void roi_pool_kernel(
    const float* __restrict__ img,
    const float* __restrict__ rois,
    float* __restrict__ out) {
  // XCD-chunk swizzle (hw round-robin: xcd = blockIdx % 8).
  const int orig = (int)blockIdx.x;
  const int newb = (orig & (NXCD - 1)) * CHUNK + (orig >> 3);
  const int r  = newb / POOLK;
  const int iy = newb - r * POOLK;

  const vfloat4 roi = *(const vfloat4*)(rois + (size_t)r * 4);

  // c = (roi * SCALE).astype(int32): non-negative, trunc == floor.
  const int x0 = __builtin_amdgcn_readfirstlane((int)(roi.x * 0.0625f));
  const int y0 = __builtin_amdgcn_readfirstlane((int)(roi.y * 0.0625f));
  const int w  = __builtin_amdgcn_readfirstlane((int)(roi.z * 0.0625f));
  const int h  = __builtin_amdgcn_readfirstlane((int)(roi.w * 0.0625f));

  // y geometry fixed for the whole strip (per reference).
  const float sy = (float)iy * ((float)h * (1.0f / 7.0f));
  const float fy = floorf(sy);
  const float ty = sy - fy;
  const int y_lo = (int)fy;
  const int y_hi = min(y_lo + 1, max(h - 1, 0));
  const int gy0 = min(max(y0 + y_lo, 0), IMG_H - 1);
  const int gy1 = min(max(y0 + y_hi, 0), IMG_H - 1);

  // Row-1 contributes iff ty != 0 AND it is a distinct image row.
  // (ty==0 -> o = top exactly; gy1==gy0 -> bot == top -> o = top exactly.)
  const bool needY = (ty != 0.0f) && (gy1 != gy0);

  const int c = (int)threadIdx.x * 4;  // 256 threads x float4 = 1024 channels
  const float* row0 = img + (size_t)gy0 * (IMG_W * IMG_C) + c;
  const float* row1 = img + (size_t)gy1 * (IMG_W * IMG_C) + c;
  float* orow = out + (((size_t)r * POOLK + iy) * POOLK) * IMG_C + c;

  const float step_x = (float)w * (1.0f / 7.0f);
  const int xmax = max(w - 1, 0);

#pragma unroll
  for (int ix = 0; ix < POOLK; ++ix) {
    const float sx = (float)ix * step_x;
    const float fx = floorf(sx);
    const float tx = sx - fx;
    const int x_lo = (int)fx;
    const int x_hi = min(x_lo + 1, xmax);
    const int gx0 = min(max(x0 + x_lo, 0), IMG_W - 1);
    const int gx1 = min(max(x0 + x_hi, 0), IMG_W - 1);
    // Column-hi contributes iff tx != 0 AND distinct column (exact f32:
    // tx*(v01-v00) is a literal 0 otherwise; only +-0 sign can differ).
    const bool needX = (tx != 0.0f) && (gx1 != gx0);

    const vfloat4 v00 = *(const vfloat4*)(row0 + (size_t)gx0 * IMG_C);
    vfloat4 top = v00;
    if (needX) {
      const vfloat4 v01 = *(const vfloat4*)(row0 + (size_t)gx1 * IMG_C);
      top = v00 + tx * (v01 - v00);
    }

    vfloat4 o = top;
    if (needY) {
      const vfloat4 v10 = *(const vfloat4*)(row1 + (size_t)gx0 * IMG_C);
      vfloat4 bot = v10;
      if (needX) {
        const vfloat4 v11 = *(const vfloat4*)(row1 + (size_t)gx1 * IMG_C);
        bot = v10 + tx * (v11 - v10);
      }
      o = top + ty * (bot - top);
    }

    __builtin_nontemporal_store(o, (vfloat4*)(orow + (size_t)ix * IMG_C));
  }
}

extern "C" void kernel_launch(void* const* d_in, const int* in_sizes, int n_in,
                              void* d_out, int out_size, void* d_ws, size_t ws_size,
                              hipStream_t stream) {
  const float* img  = (const float*)d_in[0];   // 1*128*128*1024
  const float* rois = (const float*)d_in[1];   // 1*256*4
  float* out = (float*)d_out;                  // 1*256*7*7*1024

  dim3 grid(NBLK);   // 1792 1-D, swizzled in-kernel
  dim3 block(256);
  roi_pool_kernel<<<grid, block, 0, stream>>>(img, rois, out);
}